// Round 2
// baseline (120.699 us; speedup 1.0000x reference)
//
#include <hip/hip_runtime.h>

// Problem constants (from reference): N_SUPPORT=10, N_QUERY=25, N_CLASS=2
// ns_all = 20, nq_all = 50, D = 128, F = 512
#define NS_ALL 20
#define NQ_ALL 50
#define DIM0   128
#define FEAT   512

// Output: (nq_all*ns_all, D, 2F) fp32 = 1000 x 128 x 1024
// out[q,s,d, 0:512]   = sup[s,d, :]
// out[q,s,d, 512:1024]= qry[q,d, :]
//
// In float4 units: 256 float4 per output row; rows = 50*20*128 = 128000;
// total float4 = 32,768,000 (524 MB written).
//
// R2 change: x4 manual unroll — 4 independent gather loads issued before the
// 4 nt stores, raising per-wave MLP 1 -> 4 to cover LLC read latency.

typedef float f32x4 __attribute__((ext_vector_type(4)));

__device__ __forceinline__ f32x4 gather(const f32x4* __restrict__ sup4,
                                        const f32x4* __restrict__ qry4,
                                        int i)
{
    int row = i >> 8;                    // output row (q*2560 + s*128 + d)
    int c4  = i & 255;                   // float4 column within row
    int q   = row / (NS_ALL * DIM0);     // magic-mul /2560
    int rem = row - q * (NS_ALL * DIM0); // s*128 + d

    if (c4 < (FEAT / 4)) {
        // sup[s,d,c4] : (s*128+d)*128 + c4 = rem*128 + c4
        return sup4[(rem << 7) + c4];
    } else {
        // qry[q,d,c4-128] : q*16384 + d*128 + (c4-128)
        return qry4[(q << 14) + ((rem & 127) << 7) + (c4 & 127)];
    }
}

__global__ __launch_bounds__(256) void concat_pairs_kernel(
    const f32x4* __restrict__ x4, f32x4* __restrict__ out4)
{
    const f32x4* sup4 = x4;                                   // 20*128*128 f4
    const f32x4* qry4 = x4 + NS_ALL * DIM0 * (FEAT / 4);      // offset 327680

    const int total  = NQ_ALL * NS_ALL * DIM0 * (2 * FEAT / 4); // 32,768,000
    const int stride = gridDim.x * blockDim.x;                  // 524,288

    int i = blockIdx.x * blockDim.x + threadIdx.x;

    // main unrolled-x4 loop: 4 independent loads in flight per wave
    for (; i + 3 * stride < total; i += 4 * stride) {
        f32x4 v0 = gather(sup4, qry4, i);
        f32x4 v1 = gather(sup4, qry4, i + stride);
        f32x4 v2 = gather(sup4, qry4, i + 2 * stride);
        f32x4 v3 = gather(sup4, qry4, i + 3 * stride);
        __builtin_nontemporal_store(v0, &out4[i]);
        __builtin_nontemporal_store(v1, &out4[i + stride]);
        __builtin_nontemporal_store(v2, &out4[i + 2 * stride]);
        __builtin_nontemporal_store(v3, &out4[i + 3 * stride]);
    }
    // tail
    for (; i < total; i += stride) {
        f32x4 v = gather(sup4, qry4, i);
        __builtin_nontemporal_store(v, &out4[i]);
    }
}

extern "C" void kernel_launch(void* const* d_in, const int* in_sizes, int n_in,
                              void* d_out, int out_size, void* d_ws, size_t ws_size,
                              hipStream_t stream) {
    const f32x4* x4 = (const f32x4*)d_in[0];
    f32x4* out4 = (f32x4*)d_out;

    const int threads = 256;
    const int blocks = 2048;   // 8 blocks/CU x 256 CU; grid-stride covers rest
    concat_pairs_kernel<<<blocks, threads, 0, stream>>>(x4, out4);
}

// Round 3
// 88.812 us; speedup vs baseline: 1.3590x; 1.3590x over previous
//
#include <hip/hip_runtime.h>

// Problem constants: N_SUPPORT=10, N_QUERY=25, N_CLASS=2
// ns_all = 20, nq_all = 50, D = 128, F = 512
#define NS_ALL 20
#define NQ_ALL 50
#define DIM0   128
#define FEAT   512

// Output: (50*20, 128, 1024) fp32.  out[q,s,d,0:512]=sup[s,d,:], [512:1024]=qry[q,d,:]
//
// R3: LDS-tiled producer. Block = (d, q-tile of 5, s-tile of 10).
//  - stage 10 sup rows + 5 qry rows (30 KB) in LDS once (coalesced global reads)
//  - emit 50 output rows (200 KB) from LDS with nt stores
// Global read volume: 524 MB -> 77 MB; store stream decoupled from LLC latency.

typedef float f32x4 __attribute__((ext_vector_type(4)));

#define QT 5            // q's per block
#define ST 10           // s's per block
#define F4 (FEAT / 4)   // 128 float4 per input row
// LDS: [0,1280) = sup rows (ST*128), [1280,1920) = qry rows (QT*128)
#define LDS_F4 ((QT + ST) * F4)

__global__ __launch_bounds__(256) void concat_pairs_lds_kernel(
    const f32x4* __restrict__ x4, f32x4* __restrict__ out4)
{
    const f32x4* sup4 = x4;                              // 20*128*128 f4
    const f32x4* qry4 = x4 + NS_ALL * DIM0 * F4;         // + 327680

    __shared__ f32x4 lds[LDS_F4];                        // 30 KB

    const int tid = threadIdx.x;
    // bid = (qt * 2 + st) * 128 + d   (d fastest -> concurrent blocks write
    // adjacent 4 KB output rows)
    const int bid = blockIdx.x;
    const int d   = bid & 127;
    const int tb  = bid >> 7;          // 0..19
    const int st  = tb & 1;            // 0..1   (s-tile)
    const int qt  = tb >> 1;           // 0..9   (q-tile)

    // ---- stage phase: 1920 f4 = ST rows of sup + QT rows of qry ----
    for (int j = tid; j < LDS_F4; j += 256) {
        f32x4 v;
        if (j < ST * F4) {
            int s   = j >> 7;          // row within s-tile
            int off = j & 127;
            v = sup4[((st * ST + s) * DIM0 + d) * F4 + off];
        } else {
            int jj  = j - ST * F4;
            int q   = jj >> 7;
            int off = jj & 127;
            v = qry4[((qt * QT + q) * DIM0 + d) * F4 + off];
        }
        lds[j] = v;
    }
    __syncthreads();

    // ---- emit phase: 50 output rows of 256 f4 each ----
    // thread t supplies f4 #t of the row: t<128 -> sup half, else qry half
    const f32x4* src = (tid < F4) ? &lds[tid] : &lds[ST * F4 + (tid - F4)];
    #pragma unroll
    for (int r = 0; r < QT * ST; ++r) {
        int q = r / ST;                // 0..4
        int s = r - q * ST;            // 0..9
        f32x4 v = (tid < F4) ? src[s * F4] : src[q * F4];
        int pair = (qt * QT + q) * NS_ALL + (st * ST + s);
        // out f4 index: (pair*128 + d)*256 + tid
        __builtin_nontemporal_store(v, &out4[((pair << 7) + d) * 256 + tid]);
    }
}

extern "C" void kernel_launch(void* const* d_in, const int* in_sizes, int n_in,
                              void* d_out, int out_size, void* d_ws, size_t ws_size,
                              hipStream_t stream) {
    const f32x4* x4 = (const f32x4*)d_in[0];
    f32x4* out4 = (f32x4*)d_out;

    const int threads = 256;
    const int blocks = (NQ_ALL / QT) * (NS_ALL / ST) * DIM0;  // 10*2*128 = 2560
    concat_pairs_lds_kernel<<<blocks, threads, 0, stream>>>(x4, out4);
}